// Round 23
// baseline (117.555 us; speedup 1.0000x reference)
//
#include <hip/hip_runtime.h>
#include <cstdio>

// B=32, Cin=128, S=8192, H=4, Hc=32, M=64, Cout=128
#define S_LEN 8192
#define NM 64

typedef short s8v __attribute__((ext_vector_type(8)));   // 8 bf16
typedef float f4  __attribute__((ext_vector_type(4)));
typedef _Float16 h8 __attribute__((ext_vector_type(8))); // 8 fp16

static __device__ inline unsigned short f2bf(float f) {  // RNE fp32->bf16
    unsigned int u = __builtin_bit_cast(unsigned int, f);
    u = (u + 0x7FFFu + ((u >> 16) & 1u)) >> 16;
    return (unsigned short)u;
}
static __device__ inline float bf2f(unsigned short h) {
    unsigned int u = ((unsigned int)h) << 16;
    return __builtin_bit_cast(float, u);
}

// C2-image swizzle: [128 r][32 k] tile, XOR k-bits 3..4 with (r>>1)&3
#define SW32(r, k) (((r) * 32) + ((k) ^ ((((r) >> 1) & 3) << 3)))

static __device__ __forceinline__ void glds16(const void* g, void* l) {
    __builtin_amdgcn_global_load_lds(
        (const __attribute__((address_space(1))) unsigned int*)g,
        (__attribute__((address_space(3))) unsigned int*)l, 16, 0, 0);
}

// ---------------- master trig table: tab[p] = cos(2*pi*p/8192) ----------------
__global__ __launch_bounds__(256) void gen_master(float* __restrict__ tab) {
    int p = blockIdx.x * 256 + threadIdx.x;
    tab[p] = cosf((float)p * (6.28318530717958647692f / (float)S_LEN));
}

// ---------------- fused table gen: T1frag (K3 B, fragment order) + Bimg (K1 B, LDS-image) ----
__global__ __launch_bounds__(256) void gen_tables(const float* __restrict__ tab,
                                                  short* __restrict__ T1fH,
                                                  short* __restrict__ T1fL,
                                                  _Float16* __restrict__ Bimg) {
    int tid = blockIdx.x * 256 + threadIdx.x;     // 1M
    {   // T1frag element
        int tile = tid >> 12;
        int sb = tile >> 2, kc = tile & 3;
        int uw = tid & 4095;
        int c = uw >> 5, rest = uw & 31;
        int k = kc * 32 + rest;
        int s = sb * 128 + c;
        int m = k >> 1;
        int p = (m * s + ((k & 1) << 11)) & (S_LEN - 1);
        float v = tab[p];
        unsigned short h = f2bf(v);
        T1fH[tid] = (short)h;
        T1fL[tid] = (short)f2bf(v - bf2f(h));
    }
    {   // Bimg element
        int tk = tid >> 13;
        int us = tid & 8191;
        int c = us >> 6;
        int wl = us & 63;
        int slot = wl >> 3, e = wl & 7;
        int k = ((slot ^ (c & 7)) << 3) | e;      // invert swizzle
        int kg = tk * 64 + k;
        int m = c >> 1;
        int p = (m * kg + ((c & 1) << 11)) & (S_LEN - 1);
        Bimg[tid] = (_Float16)tab[p];
    }
}

// ---------------- K1: P[ks] = x * B1 ; BM=64 BN=128 BK=64; A dist-3, B dist-2 (R12) --------
__global__ __launch_bounds__(512, 4) void dft_fwd_mfma(const float* __restrict__ x,
        const _Float16* __restrict__ Bimg, float* __restrict__ P) {
    __shared__ _Float16 abh[2][4096], abl[2][4096];   // A hi/lo [64r][64k], 8KB/buf
    __shared__ _Float16 bb[2][8192];                  // B [128c][64k], 16KB/buf
    const int t = threadIdx.x;
    const int lane = t & 63, w = t >> 6;
    const int rl = lane & 15, kq = lane >> 4;
    const int wr = w >> 2, wc = w & 3;
    const int row0 = blockIdx.x * 64;
    const int ks = blockIdx.y;                        // 0..7
    const int rA = t >> 3, sA = t & 7;
    const size_t xrow = (size_t)(row0 + rA) * S_LEN + (size_t)ks * 1024 + (size_t)sA * 8;
    const int usA = rA * 64 + ((sA ^ (rA & 7)) << 3);
    const size_t bby = (size_t)ks * 16 * 16384 + (size_t)t * 32;

    f4 acc[2][2];
    #pragma unroll
    for (int i = 0; i < 2; ++i)
        #pragma unroll
        for (int j = 0; j < 2; ++j) acc[i][j] = (f4){0.f, 0.f, 0.f, 0.f};

    f4 aP[3][2];
    h8 bP[2][2];

    #define LA_(SC, A0, A1) { A0 = *(const f4*)&x[xrow + (size_t)(SC) * 64];       \
                              A1 = *(const f4*)&x[xrow + (size_t)(SC) * 64 + 4]; }
    #define LB_(SC, B0, B1) { const char* g = (const char*)Bimg + bby +            \
                                  (size_t)(SC) * 16384;                            \
                              B0 = *(const h8*)g; B1 = *(const h8*)(g + 16); }
    #define CV_(A0, A1, NXT) { h8 hv, lv;                                          \
        _Pragma("unroll")                                                          \
        for (int e = 0; e < 4; ++e) {                                              \
            float f = A0[e]; _Float16 hh = (_Float16)f;                            \
            hv[e] = hh; lv[e] = (_Float16)(f - (float)hh);                         \
        }                                                                          \
        _Pragma("unroll")                                                          \
        for (int e = 0; e < 4; ++e) {                                              \
            float f = A1[e]; _Float16 hh = (_Float16)f;                            \
            hv[4 + e] = hh; lv[4 + e] = (_Float16)(f - (float)hh);                 \
        }                                                                          \
        *(h8*)&abh[NXT][usA] = hv;                                                 \
        *(h8*)&abl[NXT][usA] = lv; }
    #define WB_(B0, B1, NXT) { *(h8*)&bb[NXT][t * 16] = B0;                        \
                               *(h8*)&bb[NXT][t * 16 + 8] = B1; }
    #define MM_(CUR) { _Pragma("unroll")                                           \
        for (int ksl = 0; ksl < 2; ++ksl) {                                        \
            const int sb_ = ksl * 4 + kq;                                          \
            h8 Ah0, Al0, Ah1, Al1, Bv0, Bv1;                                       \
            { int r = wr * 32 + rl;      int u = r * 64 + ((sb_ ^ (r & 7)) << 3);  \
              Ah0 = *(const h8*)&abh[CUR][u]; Al0 = *(const h8*)&abl[CUR][u]; }    \
            { int r = wr * 32 + 16 + rl; int u = r * 64 + ((sb_ ^ (r & 7)) << 3);  \
              Ah1 = *(const h8*)&abh[CUR][u]; Al1 = *(const h8*)&abl[CUR][u]; }    \
            { int c = wc * 32 + rl;      int u = c * 64 + ((sb_ ^ (c & 7)) << 3);  \
              Bv0 = *(const h8*)&bb[CUR][u]; }                                     \
            { int c = wc * 32 + 16 + rl; int u = c * 64 + ((sb_ ^ (c & 7)) << 3);  \
              Bv1 = *(const h8*)&bb[CUR][u]; }                                     \
            acc[0][0] = __builtin_amdgcn_mfma_f32_16x16x32_f16(Ah0, Bv0, acc[0][0], 0, 0, 0); \
            acc[0][1] = __builtin_amdgcn_mfma_f32_16x16x32_f16(Ah0, Bv1, acc[0][1], 0, 0, 0); \
            acc[1][0] = __builtin_amdgcn_mfma_f32_16x16x32_f16(Ah1, Bv0, acc[1][0], 0, 0, 0); \
            acc[1][1] = __builtin_amdgcn_mfma_f32_16x16x32_f16(Ah1, Bv1, acc[1][1], 0, 0, 0); \
            acc[0][0] = __builtin_amdgcn_mfma_f32_16x16x32_f16(Al0, Bv0, acc[0][0], 0, 0, 0); \
            acc[0][1] = __builtin_amdgcn_mfma_f32_16x16x32_f16(Al0, Bv1, acc[0][1], 0, 0, 0); \
            acc[1][0] = __builtin_amdgcn_mfma_f32_16x16x32_f16(Al1, Bv0, acc[1][0], 0, 0, 0); \
            acc[1][1] = __builtin_amdgcn_mfma_f32_16x16x32_f16(Al1, Bv1, acc[1][1], 0, 0, 0); \
        } }
    #define BAR_ __builtin_amdgcn_sched_barrier(0);                                \
        asm volatile("s_waitcnt lgkmcnt(0)" ::: "memory");                         \
        __builtin_amdgcn_sched_barrier(0);                                         \
        __builtin_amdgcn_s_barrier();                                              \
        __builtin_amdgcn_sched_barrier(0);

    {
        f4 t0a, t0b; h8 tb0a, tb0b;
        LA_(0, t0a, t0b) LB_(0, tb0a, tb0b)
        LA_(1, aP[1][0], aP[1][1]) LA_(2, aP[2][0], aP[2][1])
        LB_(1, bP[1][0], bP[1][1])
        __builtin_amdgcn_sched_barrier(0);
        CV_(t0a, t0b, 0) WB_(tb0a, tb0b, 0)
        BAR_
    }
    #pragma unroll
    for (int s = 0; s < 16; ++s) {
        if (s + 3 <= 15) LA_(s + 3, aP[(s + 3) % 3][0], aP[(s + 3) % 3][1])
        if (s + 2 <= 15) LB_(s + 2, bP[(s + 2) & 1][0], bP[(s + 2) & 1][1])
        __builtin_amdgcn_sched_barrier(0);
        if (s + 1 <= 15) { CV_(aP[(s + 1) % 3][0], aP[(s + 1) % 3][1], (s + 1) & 1)
                           WB_(bP[(s + 1) & 1][0], bP[(s + 1) & 1][1], (s + 1) & 1) }
        MM_(s & 1)
        if (s < 15) { BAR_ }
    }

    float* Pks = P + (size_t)ks * 524288;
    #pragma unroll
    for (int mf = 0; mf < 2; ++mf)
        #pragma unroll
        for (int nf = 0; nf < 2; ++nf)
            #pragma unroll
            for (int r = 0; r < 4; ++r)
                Pks[(size_t)(row0 + wr * 32 + mf * 16 + kq * 4 + r) * 128
                    + wc * 32 + nf * 16 + rl] = acc[mf][nf][r];
}

// ---------------- ksum_t: Xt[m][row][re,im] = sum_ks P[ks][row][2m|2m+1] (LDS transpose) ----
__global__ __launch_bounds__(256) void ksum_t(const float* __restrict__ P,
                                              float* __restrict__ Xt) {
    __shared__ float xt[32][130];                 // +2 pad
    const int row0 = blockIdx.x * 32;
    const int t = threadIdx.x;
    #pragma unroll
    for (int it = 0; it < 16; ++it) {
        int li = t + it * 256;                    // 0..4095 = 32 rows x 128 cols
        int r = li >> 7, c = li & 127;
        float s = 0.f;
        #pragma unroll
        for (int ks = 0; ks < 8; ++ks)
            s += P[(size_t)ks * 524288 + (size_t)(row0 + r) * 128 + c];
        xt[r][c] = s;
    }
    __syncthreads();
    const int m = t >> 2, q = t & 3;              // m 0..63, row-quad q
    #pragma unroll
    for (int j = 0; j < 8; ++j) {
        int r = q * 8 + j;
        float2 v = make_float2(xt[r][2 * m], xt[r][2 * m + 1]);
        *(float2*)&Xt[((size_t)m * 4096 + row0 + r) * 2] = v;
    }
}

// ---------------- wtrans: wT[h][m][io] = w[h][i][o][m] (LDS 64x64 tile transpose) ----------
__global__ __launch_bounds__(256) void wtrans(const float* __restrict__ w_real,
                                              const float* __restrict__ w_imag,
                                              float* __restrict__ wTr,
                                              float* __restrict__ wTi) {
    __shared__ float tile[64][65];
    const int io0 = blockIdx.x * 64;              // 0..4032
    const int h = blockIdx.y >> 1;
    const float* src = (blockIdx.y & 1) ? w_imag : w_real;
    float* dst = (blockIdx.y & 1) ? wTi : wTr;
    const int t = threadIdx.x;
    #pragma unroll
    for (int it = 0; it < 16; ++it) {
        int li = t + it * 256;                    // 0..4095
        int r = li >> 6, c = li & 63;             // r: io offset, c: m
        tile[r][c] = src[((size_t)h * 4096 + io0 + r) * 64 + c];
    }
    __syncthreads();
    #pragma unroll
    for (int it = 0; it < 16; ++it) {
        int li = t + it * 256;
        int mr = li >> 6, ioc = li & 63;
        dst[((size_t)h * 64 + mr) * 4096 + io0 + ioc] = tile[ioc][mr];
    }
}

// ---------------- K2: mode contraction (fully coalesced reads) -> C2 image ----------------
__global__ __launch_bounds__(256) void mode_contract(const float* __restrict__ Xt,
        const float* __restrict__ wTr, const float* __restrict__ wTi,
        short* __restrict__ C2h, short* __restrict__ C2l) {
    __shared__ float xr[32][128], xi[32][128];
    __shared__ float wr[128][32], wi[128][32];
    const int m = blockIdx.x, h = blockIdx.y, t = threadIdx.x;
    #pragma unroll
    for (int it = 0; it < 16; ++it) {
        int li = t + it * 256;                    // 0..4095
        const float2 v = *(const float2*)&Xt[((size_t)m * 4096 + li) * 2];
        xr[li >> 7][li & 127] = v.x;
        xi[li >> 7][li & 127] = v.y;
        const size_t woff = (size_t)(h * 64 + m) * 4096 + li;   // li = i2*32+o
        wr[li >> 5][li & 31] = wTr[woff];
        wi[li >> 5][li & 31] = wTi[woff];
    }
    __syncthreads();
    const int o = t & 31;
    const int b0 = (t >> 5) * 4;
    float re[4] = {0.f, 0.f, 0.f, 0.f}, im[4] = {0.f, 0.f, 0.f, 0.f};
    for (int i = 0; i < 128; ++i) {
        float wrv = wr[i][o], wiv = wi[i][o];
        #pragma unroll
        for (int j = 0; j < 4; ++j) {
            float a = xr[b0 + j][i], c = xi[b0 + j][i];
            re[j] += a * wrv - c * wiv;
            im[j] += a * wiv + c * wrv;
        }
    }
    const float alpha = (m == 0) ? (1.0f / (float)S_LEN) : (2.0f / (float)S_LEN);
    const int kc = m >> 4;
    const int lk = (2 * m) & 31;
    #pragma unroll
    for (int j = 0; j < 4; ++j) {
        int row = (b0 + j) * 128 + h * 32 + o;
        float vr = alpha * re[j], vi = alpha * im[j];
        unsigned short hr = f2bf(vr), hi_ = f2bf(vi);
        float lr = vr - bf2f(hr), li_ = vi - bf2f(hi_);
        int rb = row >> 7, lr_ = row & 127;
        size_t ui = ((size_t)(rb * 4 + kc) * 4096 + SW32(lr_, lk)) >> 1;   // uint index
        ((unsigned int*)C2h)[ui] = ((unsigned int)hi_ << 16) | hr;
        ((unsigned int*)C2l)[ui] = ((unsigned int)f2bf(li_) << 16) | f2bf(lr);
    }
}

// ---------------- K3: y = C2[4096][128] * Basis[128][8192]; barrier-free K-loop ----------------
__global__ __launch_bounds__(256, 2) void idft_mfma(const short* __restrict__ C2h,
        const short* __restrict__ C2l, const short* __restrict__ T1fH,
        const short* __restrict__ T1fL, float* __restrict__ y) {
    __shared__ short ah[4][4096], al[4][4096];    // 4 kc tiles x 8KB per half = 64KB
    const int t = threadIdx.x;
    const int lane = t & 63, w = t >> 6;
    const int rl = lane & 15, kq = lane >> 4;
    const int wm = (w >> 1) * 64, wn = (w & 1) * 64;
    const int sb = blockIdx.x, rb = blockIdx.y;

    #pragma unroll
    for (int kc = 0; kc < 4; ++kc) {
        const size_t ta = (size_t)(rb * 4 + kc) * 8192;
        const int wo = w * 2048 + lane * 16;
        glds16((const char*)C2h + ta + wo,        (char*)&ah[kc][0] + w * 2048);
        glds16((const char*)C2h + ta + wo + 1024, (char*)&ah[kc][0] + w * 2048 + 1024);
        glds16((const char*)C2l + ta + wo,        (char*)&al[kc][0] + w * 2048);
        glds16((const char*)C2l + ta + wo + 1024, (char*)&al[kc][0] + w * 2048 + 1024);
    }
    __syncthreads();   // the ONLY barrier

    f4 acc[4][4];
    #pragma unroll
    for (int i = 0; i < 4; ++i)
        #pragma unroll
        for (int j = 0; j < 4; ++j) acc[i][j] = (f4){0.f, 0.f, 0.f, 0.f};

    #pragma unroll
    for (int kc = 0; kc < 4; ++kc) {
        s8v Bh[4], Bl[4];
        const size_t tb = (size_t)(sb * 4 + kc) * 8192 + (size_t)rl * 64 + (size_t)kq * 16;
        #pragma unroll
        for (int nf = 0; nf < 4; ++nf) {
            const size_t off = tb + (size_t)(wn + nf * 16) * 64;
            Bh[nf] = *(const s8v*)((const char*)T1fH + off);
            Bl[nf] = *(const s8v*)((const char*)T1fL + off);
        }
        const int kk = kq * 8;
        s8v Ah[4], Al[4];
        #pragma unroll
        for (int mf = 0; mf < 4; ++mf) {
            int us = SW32(wm + mf * 16 + rl, kk);
            Ah[mf] = *(const s8v*)&ah[kc][us];
            Al[mf] = *(const s8v*)&al[kc][us];
        }
        #pragma unroll
        for (int mf = 0; mf < 4; ++mf)
            #pragma unroll
            for (int nf = 0; nf < 4; ++nf)
                acc[mf][nf] = __builtin_amdgcn_mfma_f32_16x16x32_bf16(Ah[mf], Bh[nf], acc[mf][nf], 0, 0, 0);
        #pragma unroll
        for (int mf = 0; mf < 4; ++mf)
            #pragma unroll
            for (int nf = 0; nf < 4; ++nf)
                acc[mf][nf] = __builtin_amdgcn_mfma_f32_16x16x32_bf16(Al[mf], Bh[nf], acc[mf][nf], 0, 0, 0);
        #pragma unroll
        for (int mf = 0; mf < 4; ++mf)
            #pragma unroll
            for (int nf = 0; nf < 4; ++nf)
                acc[mf][nf] = __builtin_amdgcn_mfma_f32_16x16x32_bf16(Ah[mf], Bl[nf], acc[mf][nf], 0, 0, 0);
    }

    #pragma unroll
    for (int mf = 0; mf < 4; ++mf) {
        int rr = rb * 128 + wm + mf * 16 + kq * 4;
        #pragma unroll
        for (int nf = 0; nf < 4; ++nf) {
            int c = sb * 128 + wn + nf * 16 + rl;
            #pragma unroll
            for (int r = 0; r < 4; ++r)
                __builtin_nontemporal_store(acc[mf][nf][r], &y[(size_t)(rr + r) * S_LEN + c]);
        }
    }
}

extern "C" void kernel_launch(void* const* d_in, const int* in_sizes, int n_in,
                              void* d_out, int out_size, void* d_ws, size_t ws_size,
                              hipStream_t stream) {
    const float* x      = (const float*)d_in[0];
    const float* w_real = (const float*)d_in[1];
    const float* w_imag = (const float*)d_in[2];
    float* y = (float*)d_out;

    const size_t TBL = (size_t)S_LEN * 128;       // 1M elems
    char* w0 = (char*)d_ws;
    short* T1fH    = (short*)w0;                  // 2MB each half (K3 B fragment image)
    short* T1fL    = T1fH + TBL;
    _Float16* Bimg = (_Float16*)(T1fL + TBL);     // 2MB (K1 B LDS image)
    float* Xt      = (float*)(Bimg + TBL);        // 2MB: [64 m][4096 row][re,im]
    float* tab     = Xt + (size_t)64 * 4096 * 2;  // 32KB
    float* P       = tab + S_LEN;                 // 16MB (8 slices)
    // After ksum_t, P is dead: wT (8MB) + C2 (4MB) overlap it.
    float* wTr     = P;                           // 4MB: [4 h][64 m][4096 io]
    float* wTi     = wTr + (size_t)4 * 64 * 4096;
    short* C2h     = (short*)(wTi + (size_t)4 * 64 * 4096);
    short* C2l     = C2h + TBL;
    const size_t TOTAL = (size_t)((char*)(P + 8 * (size_t)4096 * 128) - w0);  // ~24MB
    if (ws_size < TOTAL) {
        fprintf(stderr, "kernel_launch: ws too small (%zu < %zu bytes)\n", ws_size, TOTAL);
        return;
    }

    gen_master<<<S_LEN / 256, 256, 0, stream>>>(tab);
    gen_tables<<<(S_LEN * 128) / 256, 256, 0, stream>>>(tab, T1fH, T1fL, Bimg);
    dft_fwd_mfma<<<dim3(64, 8), 512, 0, stream>>>(x, Bimg, P);
    ksum_t<<<128, 256, 0, stream>>>(P, Xt);                       // P -> Xt (P now dead)
    wtrans<<<dim3(64, 8), 256, 0, stream>>>(w_real, w_imag, wTr, wTi);  // into P region
    mode_contract<<<dim3(NM, 4), 256, 0, stream>>>(Xt, wTr, wTi, C2h, C2l);
    idft_mfma<<<dim3(64, 32), 256, 0, stream>>>(C2h, C2l, T1fH, T1fL, y);
}

// Round 24
// 115.581 us; speedup vs baseline: 1.0171x; 1.0171x over previous
//
#include <hip/hip_runtime.h>
#include <cstdio>

// B=32, Cin=128, S=8192, H=4, Hc=32, M=64, Cout=128
#define S_LEN 8192
#define NM 64

typedef short s8v __attribute__((ext_vector_type(8)));   // 8 bf16
typedef float f4  __attribute__((ext_vector_type(4)));
typedef _Float16 h8 __attribute__((ext_vector_type(8))); // 8 fp16

static __device__ inline unsigned short f2bf(float f) {  // RNE fp32->bf16
    unsigned int u = __builtin_bit_cast(unsigned int, f);
    u = (u + 0x7FFFu + ((u >> 16) & 1u)) >> 16;
    return (unsigned short)u;
}
static __device__ inline float bf2f(unsigned short h) {
    unsigned int u = ((unsigned int)h) << 16;
    return __builtin_bit_cast(float, u);
}

// C2-image swizzle: [128 r][32 k] tile, XOR k-bits 3..4 with (r>>1)&3
#define SW32(r, k) (((r) * 32) + ((k) ^ ((((r) >> 1) & 3) << 3)))

static __device__ __forceinline__ void glds16(const void* g, void* l) {
    __builtin_amdgcn_global_load_lds(
        (const __attribute__((address_space(1))) unsigned int*)g,
        (__attribute__((address_space(3))) unsigned int*)l, 16, 0, 0);
}

// ---------------- master trig table: tab[p] = cos(2*pi*p/8192) ----------------
__global__ __launch_bounds__(256) void gen_master(float* __restrict__ tab) {
    int p = blockIdx.x * 256 + threadIdx.x;
    tab[p] = cosf((float)p * (6.28318530717958647692f / (float)S_LEN));
}

// ---------------- fused table gen: T1frag (K3 B, fragment order) + Bimg (K1 B, LDS-image) ----
__global__ __launch_bounds__(256) void gen_tables(const float* __restrict__ tab,
                                                  short* __restrict__ T1fH,
                                                  short* __restrict__ T1fL,
                                                  _Float16* __restrict__ Bimg) {
    int tid = blockIdx.x * 256 + threadIdx.x;     // 1M
    {   // T1frag element
        int tile = tid >> 12;
        int sb = tile >> 2, kc = tile & 3;
        int uw = tid & 4095;
        int c = uw >> 5, rest = uw & 31;
        int k = kc * 32 + rest;
        int s = sb * 128 + c;
        int m = k >> 1;
        int p = (m * s + ((k & 1) << 11)) & (S_LEN - 1);
        float v = tab[p];
        unsigned short h = f2bf(v);
        T1fH[tid] = (short)h;
        T1fL[tid] = (short)f2bf(v - bf2f(h));
    }
    {   // Bimg element
        int tk = tid >> 13;
        int us = tid & 8191;
        int c = us >> 6;
        int wl = us & 63;
        int slot = wl >> 3, e = wl & 7;
        int k = ((slot ^ (c & 7)) << 3) | e;      // invert swizzle
        int kg = tk * 64 + k;
        int m = c >> 1;
        int p = (m * kg + ((c & 1) << 11)) & (S_LEN - 1);
        Bimg[tid] = (_Float16)tab[p];
    }
}

// ---------------- K1: P[ks] = x * B1 ; BM=64 BN=128 BK=64; A SINGLE fp16 ----------------
// R20 structure, A lo-pass dropped (R15-validated numerics): 8 MFMA/step, LDS 48KB.
__global__ __launch_bounds__(512, 4) void dft_fwd_mfma(const float* __restrict__ x,
        const _Float16* __restrict__ Bimg, float* __restrict__ P) {
    __shared__ _Float16 ab[2][4096];                  // A fp16 [64r][64k], 8KB/buf
    __shared__ _Float16 bb[2][8192];                  // B [128c][64k], 16KB/buf
    const int t = threadIdx.x;
    const int lane = t & 63, w = t >> 6;
    const int rl = lane & 15, kq = lane >> 4;
    const int wr = w >> 2, wc = w & 3;
    const int row0 = blockIdx.x * 64;
    const int ks = blockIdx.y;                        // 0..7
    const int rA = t >> 3, sA = t & 7;
    const size_t xrow = (size_t)(row0 + rA) * S_LEN + (size_t)ks * 1024 + (size_t)sA * 8;
    const int usA = rA * 64 + ((sA ^ (rA & 7)) << 3);
    const size_t bby = (size_t)ks * 16 * 16384 + (size_t)t * 32;

    f4 acc[2][2];
    #pragma unroll
    for (int i = 0; i < 2; ++i)
        #pragma unroll
        for (int j = 0; j < 2; ++j) acc[i][j] = (f4){0.f, 0.f, 0.f, 0.f};

    f4 aP[3][2];
    h8 bP[2][2];

    #define LA_(SC, A0, A1) { A0 = *(const f4*)&x[xrow + (size_t)(SC) * 64];       \
                              A1 = *(const f4*)&x[xrow + (size_t)(SC) * 64 + 4]; }
    #define LB_(SC, B0, B1) { const char* g = (const char*)Bimg + bby +            \
                                  (size_t)(SC) * 16384;                            \
                              B0 = *(const h8*)g; B1 = *(const h8*)(g + 16); }
    #define CV_(A0, A1, NXT) { h8 hv;                                              \
        _Pragma("unroll")                                                          \
        for (int e = 0; e < 4; ++e) hv[e] = (_Float16)A0[e];                       \
        _Pragma("unroll")                                                          \
        for (int e = 0; e < 4; ++e) hv[4 + e] = (_Float16)A1[e];                   \
        *(h8*)&ab[NXT][usA] = hv; }
    #define WB_(B0, B1, NXT) { *(h8*)&bb[NXT][t * 16] = B0;                        \
                               *(h8*)&bb[NXT][t * 16 + 8] = B1; }
    #define MM_(CUR) { _Pragma("unroll")                                           \
        for (int ksl = 0; ksl < 2; ++ksl) {                                        \
            const int sb_ = ksl * 4 + kq;                                          \
            h8 Av0, Av1, Bv0, Bv1;                                                 \
            { int r = wr * 32 + rl;      int u = r * 64 + ((sb_ ^ (r & 7)) << 3);  \
              Av0 = *(const h8*)&ab[CUR][u]; }                                     \
            { int r = wr * 32 + 16 + rl; int u = r * 64 + ((sb_ ^ (r & 7)) << 3);  \
              Av1 = *(const h8*)&ab[CUR][u]; }                                     \
            { int c = wc * 32 + rl;      int u = c * 64 + ((sb_ ^ (c & 7)) << 3);  \
              Bv0 = *(const h8*)&bb[CUR][u]; }                                     \
            { int c = wc * 32 + 16 + rl; int u = c * 64 + ((sb_ ^ (c & 7)) << 3);  \
              Bv1 = *(const h8*)&bb[CUR][u]; }                                     \
            acc[0][0] = __builtin_amdgcn_mfma_f32_16x16x32_f16(Av0, Bv0, acc[0][0], 0, 0, 0); \
            acc[0][1] = __builtin_amdgcn_mfma_f32_16x16x32_f16(Av0, Bv1, acc[0][1], 0, 0, 0); \
            acc[1][0] = __builtin_amdgcn_mfma_f32_16x16x32_f16(Av1, Bv0, acc[1][0], 0, 0, 0); \
            acc[1][1] = __builtin_amdgcn_mfma_f32_16x16x32_f16(Av1, Bv1, acc[1][1], 0, 0, 0); \
        } }
    #define BAR_ __builtin_amdgcn_sched_barrier(0);                                \
        asm volatile("s_waitcnt lgkmcnt(0)" ::: "memory");                         \
        __builtin_amdgcn_sched_barrier(0);                                         \
        __builtin_amdgcn_s_barrier();                                              \
        __builtin_amdgcn_sched_barrier(0);

    {
        f4 t0a, t0b; h8 tb0a, tb0b;
        LA_(0, t0a, t0b) LB_(0, tb0a, tb0b)
        LA_(1, aP[1][0], aP[1][1]) LA_(2, aP[2][0], aP[2][1])
        LB_(1, bP[1][0], bP[1][1])
        __builtin_amdgcn_sched_barrier(0);
        CV_(t0a, t0b, 0) WB_(tb0a, tb0b, 0)
        BAR_
    }
    #pragma unroll
    for (int s = 0; s < 16; ++s) {
        if (s + 3 <= 15) LA_(s + 3, aP[(s + 3) % 3][0], aP[(s + 3) % 3][1])
        if (s + 2 <= 15) LB_(s + 2, bP[(s + 2) & 1][0], bP[(s + 2) & 1][1])
        __builtin_amdgcn_sched_barrier(0);
        if (s + 1 <= 15) { CV_(aP[(s + 1) % 3][0], aP[(s + 1) % 3][1], (s + 1) & 1)
                           WB_(bP[(s + 1) & 1][0], bP[(s + 1) & 1][1], (s + 1) & 1) }
        MM_(s & 1)
        if (s < 15) { BAR_ }
    }

    float* Pks = P + (size_t)ks * 524288;
    #pragma unroll
    for (int mf = 0; mf < 2; ++mf)
        #pragma unroll
        for (int nf = 0; nf < 2; ++nf)
            #pragma unroll
            for (int r = 0; r < 4; ++r)
                Pks[(size_t)(row0 + wr * 32 + mf * 16 + kq * 4 + r) * 128
                    + wc * 32 + nf * 16 + rl] = acc[mf][nf][r];
}

// ---------------- ksum_t: Xt[m][row][re,im] = sum_ks P[ks][row][2m|2m+1] (LDS transpose) ----
__global__ __launch_bounds__(256) void ksum_t(const float* __restrict__ P,
                                              float* __restrict__ Xt) {
    __shared__ float xt[32][130];                 // +2 pad
    const int row0 = blockIdx.x * 32;
    const int t = threadIdx.x;
    #pragma unroll
    for (int it = 0; it < 16; ++it) {
        int li = t + it * 256;                    // 0..4095 = 32 rows x 128 cols
        int r = li >> 7, c = li & 127;
        float s = 0.f;
        #pragma unroll
        for (int ks = 0; ks < 8; ++ks)
            s += P[(size_t)ks * 524288 + (size_t)(row0 + r) * 128 + c];
        xt[r][c] = s;
    }
    __syncthreads();
    const int m = t >> 2, q = t & 3;              // m 0..63, row-quad q
    #pragma unroll
    for (int j = 0; j < 8; ++j) {
        int r = q * 8 + j;
        float2 v = make_float2(xt[r][2 * m], xt[r][2 * m + 1]);
        *(float2*)&Xt[((size_t)m * 4096 + row0 + r) * 2] = v;
    }
}

// ---------------- wtrans: wT[h][m][io] = w[h][i][o][m] (LDS 64x64 tile transpose) ----------
__global__ __launch_bounds__(256) void wtrans(const float* __restrict__ w_real,
                                              const float* __restrict__ w_imag,
                                              float* __restrict__ wTr,
                                              float* __restrict__ wTi) {
    __shared__ float tile[64][65];
    const int io0 = blockIdx.x * 64;              // 0..4032
    const int h = blockIdx.y >> 1;
    const float* src = (blockIdx.y & 1) ? w_imag : w_real;
    float* dst = (blockIdx.y & 1) ? wTi : wTr;
    const int t = threadIdx.x;
    #pragma unroll
    for (int it = 0; it < 16; ++it) {
        int li = t + it * 256;                    // 0..4095
        int r = li >> 6, c = li & 63;             // r: io offset, c: m
        tile[r][c] = src[((size_t)h * 4096 + io0 + r) * 64 + c];
    }
    __syncthreads();
    #pragma unroll
    for (int it = 0; it < 16; ++it) {
        int li = t + it * 256;
        int mr = li >> 6, ioc = li & 63;
        dst[((size_t)h * 64 + mr) * 4096 + io0 + ioc] = tile[ioc][mr];
    }
}

// ---------------- K2: mode contraction (fully coalesced reads) -> C2 image ----------------
__global__ __launch_bounds__(256) void mode_contract(const float* __restrict__ Xt,
        const float* __restrict__ wTr, const float* __restrict__ wTi,
        short* __restrict__ C2h, short* __restrict__ C2l) {
    __shared__ float xr[32][128], xi[32][128];
    __shared__ float wr[128][32], wi[128][32];
    const int m = blockIdx.x, h = blockIdx.y, t = threadIdx.x;
    #pragma unroll
    for (int it = 0; it < 16; ++it) {
        int li = t + it * 256;                    // 0..4095
        const float2 v = *(const float2*)&Xt[((size_t)m * 4096 + li) * 2];
        xr[li >> 7][li & 127] = v.x;
        xi[li >> 7][li & 127] = v.y;
        const size_t woff = (size_t)(h * 64 + m) * 4096 + li;   // li = i2*32+o
        wr[li >> 5][li & 31] = wTr[woff];
        wi[li >> 5][li & 31] = wTi[woff];
    }
    __syncthreads();
    const int o = t & 31;
    const int b0 = (t >> 5) * 4;
    float re[4] = {0.f, 0.f, 0.f, 0.f}, im[4] = {0.f, 0.f, 0.f, 0.f};
    for (int i = 0; i < 128; ++i) {
        float wrv = wr[i][o], wiv = wi[i][o];
        #pragma unroll
        for (int j = 0; j < 4; ++j) {
            float a = xr[b0 + j][i], c = xi[b0 + j][i];
            re[j] += a * wrv - c * wiv;
            im[j] += a * wiv + c * wrv;
        }
    }
    const float alpha = (m == 0) ? (1.0f / (float)S_LEN) : (2.0f / (float)S_LEN);
    const int kc = m >> 4;
    const int lk = (2 * m) & 31;
    #pragma unroll
    for (int j = 0; j < 4; ++j) {
        int row = (b0 + j) * 128 + h * 32 + o;
        float vr = alpha * re[j], vi = alpha * im[j];
        unsigned short hr = f2bf(vr), hi_ = f2bf(vi);
        float lr = vr - bf2f(hr), li_ = vi - bf2f(hi_);
        int rb = row >> 7, lr_ = row & 127;
        size_t ui = ((size_t)(rb * 4 + kc) * 4096 + SW32(lr_, lk)) >> 1;   // uint index
        ((unsigned int*)C2h)[ui] = ((unsigned int)hi_ << 16) | hr;
        ((unsigned int*)C2l)[ui] = ((unsigned int)f2bf(li_) << 16) | f2bf(lr);
    }
}

// ---------------- K3: y = C2[4096][128] * Basis[128][8192]; barrier-free K-loop ----------------
__global__ __launch_bounds__(256, 2) void idft_mfma(const short* __restrict__ C2h,
        const short* __restrict__ C2l, const short* __restrict__ T1fH,
        const short* __restrict__ T1fL, float* __restrict__ y) {
    __shared__ short ah[4][4096], al[4][4096];    // 4 kc tiles x 8KB per half = 64KB
    const int t = threadIdx.x;
    const int lane = t & 63, w = t >> 6;
    const int rl = lane & 15, kq = lane >> 4;
    const int wm = (w >> 1) * 64, wn = (w & 1) * 64;
    const int sb = blockIdx.x, rb = blockIdx.y;

    #pragma unroll
    for (int kc = 0; kc < 4; ++kc) {
        const size_t ta = (size_t)(rb * 4 + kc) * 8192;
        const int wo = w * 2048 + lane * 16;
        glds16((const char*)C2h + ta + wo,        (char*)&ah[kc][0] + w * 2048);
        glds16((const char*)C2h + ta + wo + 1024, (char*)&ah[kc][0] + w * 2048 + 1024);
        glds16((const char*)C2l + ta + wo,        (char*)&al[kc][0] + w * 2048);
        glds16((const char*)C2l + ta + wo + 1024, (char*)&al[kc][0] + w * 2048 + 1024);
    }
    __syncthreads();   // the ONLY barrier

    f4 acc[4][4];
    #pragma unroll
    for (int i = 0; i < 4; ++i)
        #pragma unroll
        for (int j = 0; j < 4; ++j) acc[i][j] = (f4){0.f, 0.f, 0.f, 0.f};

    #pragma unroll
    for (int kc = 0; kc < 4; ++kc) {
        s8v Bh[4], Bl[4];
        const size_t tb = (size_t)(sb * 4 + kc) * 8192 + (size_t)rl * 64 + (size_t)kq * 16;
        #pragma unroll
        for (int nf = 0; nf < 4; ++nf) {
            const size_t off = tb + (size_t)(wn + nf * 16) * 64;
            Bh[nf] = *(const s8v*)((const char*)T1fH + off);
            Bl[nf] = *(const s8v*)((const char*)T1fL + off);
        }
        const int kk = kq * 8;
        s8v Ah[4], Al[4];
        #pragma unroll
        for (int mf = 0; mf < 4; ++mf) {
            int us = SW32(wm + mf * 16 + rl, kk);
            Ah[mf] = *(const s8v*)&ah[kc][us];
            Al[mf] = *(const s8v*)&al[kc][us];
        }
        #pragma unroll
        for (int mf = 0; mf < 4; ++mf)
            #pragma unroll
            for (int nf = 0; nf < 4; ++nf)
                acc[mf][nf] = __builtin_amdgcn_mfma_f32_16x16x32_bf16(Ah[mf], Bh[nf], acc[mf][nf], 0, 0, 0);
        #pragma unroll
        for (int mf = 0; mf < 4; ++mf)
            #pragma unroll
            for (int nf = 0; nf < 4; ++nf)
                acc[mf][nf] = __builtin_amdgcn_mfma_f32_16x16x32_bf16(Al[mf], Bh[nf], acc[mf][nf], 0, 0, 0);
        #pragma unroll
        for (int mf = 0; mf < 4; ++mf)
            #pragma unroll
            for (int nf = 0; nf < 4; ++nf)
                acc[mf][nf] = __builtin_amdgcn_mfma_f32_16x16x32_bf16(Ah[mf], Bl[nf], acc[mf][nf], 0, 0, 0);
    }

    #pragma unroll
    for (int mf = 0; mf < 4; ++mf) {
        int rr = rb * 128 + wm + mf * 16 + kq * 4;
        #pragma unroll
        for (int nf = 0; nf < 4; ++nf) {
            int c = sb * 128 + wn + nf * 16 + rl;
            #pragma unroll
            for (int r = 0; r < 4; ++r)
                __builtin_nontemporal_store(acc[mf][nf][r], &y[(size_t)(rr + r) * S_LEN + c]);
        }
    }
}

extern "C" void kernel_launch(void* const* d_in, const int* in_sizes, int n_in,
                              void* d_out, int out_size, void* d_ws, size_t ws_size,
                              hipStream_t stream) {
    const float* x      = (const float*)d_in[0];
    const float* w_real = (const float*)d_in[1];
    const float* w_imag = (const float*)d_in[2];
    float* y = (float*)d_out;

    const size_t TBL = (size_t)S_LEN * 128;       // 1M elems
    char* w0 = (char*)d_ws;
    short* T1fH    = (short*)w0;                  // 2MB each half (K3 B fragment image)
    short* T1fL    = T1fH + TBL;
    _Float16* Bimg = (_Float16*)(T1fL + TBL);     // 2MB (K1 B LDS image)
    float* Xt      = (float*)(Bimg + TBL);        // 2MB: [64 m][4096 row][re,im]
    float* tab     = Xt + (size_t)64 * 4096 * 2;  // 32KB
    float* P       = tab + S_LEN;                 // 16MB (8 slices)
    // After ksum_t, P is dead: wT (8MB) + C2 (4MB) overlap it.
    float* wTr     = P;                           // 4MB: [4 h][64 m][4096 io]
    float* wTi     = wTr + (size_t)4 * 64 * 4096;
    short* C2h     = (short*)(wTi + (size_t)4 * 64 * 4096);
    short* C2l     = C2h + TBL;
    const size_t TOTAL = (size_t)((char*)(P + 8 * (size_t)4096 * 128) - w0);  // ~24MB
    if (ws_size < TOTAL) {
        fprintf(stderr, "kernel_launch: ws too small (%zu < %zu bytes)\n", ws_size, TOTAL);
        return;
    }

    gen_master<<<S_LEN / 256, 256, 0, stream>>>(tab);
    gen_tables<<<(S_LEN * 128) / 256, 256, 0, stream>>>(tab, T1fH, T1fL, Bimg);
    dft_fwd_mfma<<<dim3(64, 8), 512, 0, stream>>>(x, Bimg, P);
    ksum_t<<<128, 256, 0, stream>>>(P, Xt);                       // P -> Xt (P now dead)
    wtrans<<<dim3(64, 8), 256, 0, stream>>>(w_real, w_imag, wTr, wTi);  // into P region
    mode_contract<<<dim3(NM, 4), 256, 0, stream>>>(Xt, wTr, wTi, C2h, C2l);
    idft_mfma<<<dim3(64, 32), 256, 0, stream>>>(C2h, C2l, T1fH, T1fL, y);
}

// Round 25
// 110.063 us; speedup vs baseline: 1.0681x; 1.0501x over previous
//
#include <hip/hip_runtime.h>
#include <cstdio>

// B=32, Cin=128, S=8192, H=4, Hc=32, M=64, Cout=128
#define S_LEN 8192
#define NM 64

typedef short s8v __attribute__((ext_vector_type(8)));   // 8 bf16
typedef float f4  __attribute__((ext_vector_type(4)));
typedef _Float16 h8 __attribute__((ext_vector_type(8))); // 8 fp16

static __device__ inline unsigned short f2bf(float f) {  // RNE fp32->bf16
    unsigned int u = __builtin_bit_cast(unsigned int, f);
    u = (u + 0x7FFFu + ((u >> 16) & 1u)) >> 16;
    return (unsigned short)u;
}
static __device__ inline float bf2f(unsigned short h) {
    unsigned int u = ((unsigned int)h) << 16;
    return __builtin_bit_cast(float, u);
}

// C2-image swizzle: [128 r][32 k] tile, XOR k-bits 3..4 with (r>>1)&3
#define SW32(r, k) (((r) * 32) + ((k) ^ ((((r) >> 1) & 3) << 3)))

static __device__ __forceinline__ void glds16(const void* g, void* l) {
    __builtin_amdgcn_global_load_lds(
        (const __attribute__((address_space(1))) unsigned int*)g,
        (__attribute__((address_space(3))) unsigned int*)l, 16, 0, 0);
}

// ---------------- master trig table: tab[p] = cos(2*pi*p/8192) ----------------
__global__ __launch_bounds__(256) void gen_master(float* __restrict__ tab) {
    int p = blockIdx.x * 256 + threadIdx.x;
    tab[p] = cosf((float)p * (6.28318530717958647692f / (float)S_LEN));
}

// ---------------- fused table gen: T1frag (K3 B, fragment order) + Bimg (K1 B, LDS-image) ----
__global__ __launch_bounds__(256) void gen_tables(const float* __restrict__ tab,
                                                  short* __restrict__ T1fH,
                                                  short* __restrict__ T1fL,
                                                  _Float16* __restrict__ Bimg) {
    int tid = blockIdx.x * 256 + threadIdx.x;     // 1M
    {   // T1frag element
        int tile = tid >> 12;
        int sb = tile >> 2, kc = tile & 3;
        int uw = tid & 4095;
        int c = uw >> 5, rest = uw & 31;
        int k = kc * 32 + rest;
        int s = sb * 128 + c;
        int m = k >> 1;
        int p = (m * s + ((k & 1) << 11)) & (S_LEN - 1);
        float v = tab[p];
        unsigned short h = f2bf(v);
        T1fH[tid] = (short)h;
        T1fL[tid] = (short)f2bf(v - bf2f(h));
    }
    {   // Bimg element
        int tk = tid >> 13;
        int us = tid & 8191;
        int c = us >> 6;
        int wl = us & 63;
        int slot = wl >> 3, e = wl & 7;
        int k = ((slot ^ (c & 7)) << 3) | e;      // invert swizzle
        int kg = tk * 64 + k;
        int m = c >> 1;
        int p = (m * kg + ((c & 1) << 11)) & (S_LEN - 1);
        Bimg[tid] = (_Float16)tab[p];
    }
}

// ---------------- K1: P[ks] = x * B1 ; BM=64 BN=128 BK=64; A SINGLE fp16 (R24) ----------------
__global__ __launch_bounds__(512, 4) void dft_fwd_mfma(const float* __restrict__ x,
        const _Float16* __restrict__ Bimg, float* __restrict__ P) {
    __shared__ _Float16 ab[2][4096];                  // A fp16 [64r][64k], 8KB/buf
    __shared__ _Float16 bb[2][8192];                  // B [128c][64k], 16KB/buf
    const int t = threadIdx.x;
    const int lane = t & 63, w = t >> 6;
    const int rl = lane & 15, kq = lane >> 4;
    const int wr = w >> 2, wc = w & 3;
    const int row0 = blockIdx.x * 64;
    const int ks = blockIdx.y;                        // 0..7
    const int rA = t >> 3, sA = t & 7;
    const size_t xrow = (size_t)(row0 + rA) * S_LEN + (size_t)ks * 1024 + (size_t)sA * 8;
    const int usA = rA * 64 + ((sA ^ (rA & 7)) << 3);
    const size_t bby = (size_t)ks * 16 * 16384 + (size_t)t * 32;

    f4 acc[2][2];
    #pragma unroll
    for (int i = 0; i < 2; ++i)
        #pragma unroll
        for (int j = 0; j < 2; ++j) acc[i][j] = (f4){0.f, 0.f, 0.f, 0.f};

    f4 aP[3][2];
    h8 bP[2][2];

    #define LA_(SC, A0, A1) { A0 = *(const f4*)&x[xrow + (size_t)(SC) * 64];       \
                              A1 = *(const f4*)&x[xrow + (size_t)(SC) * 64 + 4]; }
    #define LB_(SC, B0, B1) { const char* g = (const char*)Bimg + bby +            \
                                  (size_t)(SC) * 16384;                            \
                              B0 = *(const h8*)g; B1 = *(const h8*)(g + 16); }
    #define CV_(A0, A1, NXT) { h8 hv;                                              \
        _Pragma("unroll")                                                          \
        for (int e = 0; e < 4; ++e) hv[e] = (_Float16)A0[e];                       \
        _Pragma("unroll")                                                          \
        for (int e = 0; e < 4; ++e) hv[4 + e] = (_Float16)A1[e];                   \
        *(h8*)&ab[NXT][usA] = hv; }
    #define WB_(B0, B1, NXT) { *(h8*)&bb[NXT][t * 16] = B0;                        \
                               *(h8*)&bb[NXT][t * 16 + 8] = B1; }
    #define MM_(CUR) { _Pragma("unroll")                                           \
        for (int ksl = 0; ksl < 2; ++ksl) {                                        \
            const int sb_ = ksl * 4 + kq;                                          \
            h8 Av0, Av1, Bv0, Bv1;                                                 \
            { int r = wr * 32 + rl;      int u = r * 64 + ((sb_ ^ (r & 7)) << 3);  \
              Av0 = *(const h8*)&ab[CUR][u]; }                                     \
            { int r = wr * 32 + 16 + rl; int u = r * 64 + ((sb_ ^ (r & 7)) << 3);  \
              Av1 = *(const h8*)&ab[CUR][u]; }                                     \
            { int c = wc * 32 + rl;      int u = c * 64 + ((sb_ ^ (c & 7)) << 3);  \
              Bv0 = *(const h8*)&bb[CUR][u]; }                                     \
            { int c = wc * 32 + 16 + rl; int u = c * 64 + ((sb_ ^ (c & 7)) << 3);  \
              Bv1 = *(const h8*)&bb[CUR][u]; }                                     \
            acc[0][0] = __builtin_amdgcn_mfma_f32_16x16x32_f16(Av0, Bv0, acc[0][0], 0, 0, 0); \
            acc[0][1] = __builtin_amdgcn_mfma_f32_16x16x32_f16(Av0, Bv1, acc[0][1], 0, 0, 0); \
            acc[1][0] = __builtin_amdgcn_mfma_f32_16x16x32_f16(Av1, Bv0, acc[1][0], 0, 0, 0); \
            acc[1][1] = __builtin_amdgcn_mfma_f32_16x16x32_f16(Av1, Bv1, acc[1][1], 0, 0, 0); \
        } }
    #define BAR_ __builtin_amdgcn_sched_barrier(0);                                \
        asm volatile("s_waitcnt lgkmcnt(0)" ::: "memory");                         \
        __builtin_amdgcn_sched_barrier(0);                                         \
        __builtin_amdgcn_s_barrier();                                              \
        __builtin_amdgcn_sched_barrier(0);

    {
        f4 t0a, t0b; h8 tb0a, tb0b;
        LA_(0, t0a, t0b) LB_(0, tb0a, tb0b)
        LA_(1, aP[1][0], aP[1][1]) LA_(2, aP[2][0], aP[2][1])
        LB_(1, bP[1][0], bP[1][1])
        __builtin_amdgcn_sched_barrier(0);
        CV_(t0a, t0b, 0) WB_(tb0a, tb0b, 0)
        BAR_
    }
    #pragma unroll
    for (int s = 0; s < 16; ++s) {
        if (s + 3 <= 15) LA_(s + 3, aP[(s + 3) % 3][0], aP[(s + 3) % 3][1])
        if (s + 2 <= 15) LB_(s + 2, bP[(s + 2) & 1][0], bP[(s + 2) & 1][1])
        __builtin_amdgcn_sched_barrier(0);
        if (s + 1 <= 15) { CV_(aP[(s + 1) % 3][0], aP[(s + 1) % 3][1], (s + 1) & 1)
                           WB_(bP[(s + 1) & 1][0], bP[(s + 1) & 1][1], (s + 1) & 1) }
        MM_(s & 1)
        if (s < 15) { BAR_ }
    }

    float* Pks = P + (size_t)ks * 524288;
    #pragma unroll
    for (int mf = 0; mf < 2; ++mf)
        #pragma unroll
        for (int nf = 0; nf < 2; ++nf)
            #pragma unroll
            for (int r = 0; r < 4; ++r)
                Pks[(size_t)(row0 + wr * 32 + mf * 16 + kq * 4 + r) * 128
                    + wc * 32 + nf * 16 + rl] = acc[mf][nf][r];
}

// ---------------- ksum_t: Xt[m][row][re,im] = sum_ks P[ks][row][2m|2m+1] (LDS transpose) ----
__global__ __launch_bounds__(256) void ksum_t(const float* __restrict__ P,
                                              float* __restrict__ Xt) {
    __shared__ float xt[32][130];                 // +2 pad
    const int row0 = blockIdx.x * 32;
    const int t = threadIdx.x;
    #pragma unroll
    for (int it = 0; it < 16; ++it) {
        int li = t + it * 256;                    // 0..4095 = 32 rows x 128 cols
        int r = li >> 7, c = li & 127;
        float s = 0.f;
        #pragma unroll
        for (int ks = 0; ks < 8; ++ks)
            s += P[(size_t)ks * 524288 + (size_t)(row0 + r) * 128 + c];
        xt[r][c] = s;
    }
    __syncthreads();
    const int m = t >> 2, q = t & 3;              // m 0..63, row-quad q
    #pragma unroll
    for (int j = 0; j < 8; ++j) {
        int r = q * 8 + j;
        float2 v = make_float2(xt[r][2 * m], xt[r][2 * m + 1]);
        *(float2*)&Xt[((size_t)m * 4096 + row0 + r) * 2] = v;
    }
}

// ---------------- wtrans: wT[h][m][io] = w[h][i][o][m] (LDS 64x64 tile transpose) ----------
__global__ __launch_bounds__(256) void wtrans(const float* __restrict__ w_real,
                                              const float* __restrict__ w_imag,
                                              float* __restrict__ wTr,
                                              float* __restrict__ wTi) {
    __shared__ float tile[64][65];
    const int io0 = blockIdx.x * 64;              // 0..4032
    const int h = blockIdx.y >> 1;
    const float* src = (blockIdx.y & 1) ? w_imag : w_real;
    float* dst = (blockIdx.y & 1) ? wTi : wTr;
    const int t = threadIdx.x;
    #pragma unroll
    for (int it = 0; it < 16; ++it) {
        int li = t + it * 256;                    // 0..4095
        int r = li >> 6, c = li & 63;             // r: io offset, c: m
        tile[r][c] = src[((size_t)h * 4096 + io0 + r) * 64 + c];
    }
    __syncthreads();
    #pragma unroll
    for (int it = 0; it < 16; ++it) {
        int li = t + it * 256;
        int mr = li >> 6, ioc = li & 63;
        dst[((size_t)h * 64 + mr) * 4096 + io0 + ioc] = tile[ioc][mr];
    }
}

// ---------------- K2: mode contraction (fully coalesced reads) -> C2 image ----------------
__global__ __launch_bounds__(256) void mode_contract(const float* __restrict__ Xt,
        const float* __restrict__ wTr, const float* __restrict__ wTi,
        short* __restrict__ C2h, short* __restrict__ C2l) {
    __shared__ float xr[32][128], xi[32][128];
    __shared__ float wr[128][32], wi[128][32];
    const int m = blockIdx.x, h = blockIdx.y, t = threadIdx.x;
    #pragma unroll
    for (int it = 0; it < 16; ++it) {
        int li = t + it * 256;                    // 0..4095
        const float2 v = *(const float2*)&Xt[((size_t)m * 4096 + li) * 2];
        xr[li >> 7][li & 127] = v.x;
        xi[li >> 7][li & 127] = v.y;
        const size_t woff = (size_t)(h * 64 + m) * 4096 + li;   // li = i2*32+o
        wr[li >> 5][li & 31] = wTr[woff];
        wi[li >> 5][li & 31] = wTi[woff];
    }
    __syncthreads();
    const int o = t & 31;
    const int b0 = (t >> 5) * 4;
    float re[4] = {0.f, 0.f, 0.f, 0.f}, im[4] = {0.f, 0.f, 0.f, 0.f};
    for (int i = 0; i < 128; ++i) {
        float wrv = wr[i][o], wiv = wi[i][o];
        #pragma unroll
        for (int j = 0; j < 4; ++j) {
            float a = xr[b0 + j][i], c = xi[b0 + j][i];
            re[j] += a * wrv - c * wiv;
            im[j] += a * wiv + c * wrv;
        }
    }
    const float alpha = (m == 0) ? (1.0f / (float)S_LEN) : (2.0f / (float)S_LEN);
    const int kc = m >> 4;
    const int lk = (2 * m) & 31;
    #pragma unroll
    for (int j = 0; j < 4; ++j) {
        int row = (b0 + j) * 128 + h * 32 + o;
        float vr = alpha * re[j], vi = alpha * im[j];
        unsigned short hr = f2bf(vr), hi_ = f2bf(vi);
        float lr = vr - bf2f(hr), li_ = vi - bf2f(hi_);
        int rb = row >> 7, lr_ = row & 127;
        size_t ui = ((size_t)(rb * 4 + kc) * 4096 + SW32(lr_, lk)) >> 1;   // uint index
        ((unsigned int*)C2h)[ui] = ((unsigned int)hi_ << 16) | hr;
        ((unsigned int*)C2l)[ui] = ((unsigned int)f2bf(li_) << 16) | f2bf(lr);
    }
}

// ---------------- K3: y = C2[4096][128] * Basis[128][8192]; SINGLE bf16 (hi only) ----------
// Error budget: bf16-rounding C2 and basis each contribute ~3e-4 to y (std 0.11) --
// negligible vs measured 3.9e-3 / threshold 15.2e-3. 16 MFMA/kc, LDS 32KB, 4 blocks/CU.
__global__ __launch_bounds__(256, 4) void idft_mfma(const short* __restrict__ C2h,
        const short* __restrict__ C2l, const short* __restrict__ T1fH,
        const short* __restrict__ T1fL, float* __restrict__ y) {
    __shared__ short ah[4][4096];                 // 4 kc tiles x 8KB = 32KB
    const int t = threadIdx.x;
    const int lane = t & 63, w = t >> 6;
    const int rl = lane & 15, kq = lane >> 4;
    const int wm = (w >> 1) * 64, wn = (w & 1) * 64;
    const int sb = blockIdx.x, rb = blockIdx.y;

    #pragma unroll
    for (int kc = 0; kc < 4; ++kc) {
        const size_t ta = (size_t)(rb * 4 + kc) * 8192;
        const int wo = w * 2048 + lane * 16;
        glds16((const char*)C2h + ta + wo,        (char*)&ah[kc][0] + w * 2048);
        glds16((const char*)C2h + ta + wo + 1024, (char*)&ah[kc][0] + w * 2048 + 1024);
    }
    __syncthreads();   // the ONLY barrier

    f4 acc[4][4];
    #pragma unroll
    for (int i = 0; i < 4; ++i)
        #pragma unroll
        for (int j = 0; j < 4; ++j) acc[i][j] = (f4){0.f, 0.f, 0.f, 0.f};

    #pragma unroll
    for (int kc = 0; kc < 4; ++kc) {
        s8v Bh[4];
        const size_t tb = (size_t)(sb * 4 + kc) * 8192 + (size_t)rl * 64 + (size_t)kq * 16;
        #pragma unroll
        for (int nf = 0; nf < 4; ++nf)
            Bh[nf] = *(const s8v*)((const char*)T1fH + tb + (size_t)(wn + nf * 16) * 64);
        const int kk = kq * 8;
        s8v Ah[4];
        #pragma unroll
        for (int mf = 0; mf < 4; ++mf)
            Ah[mf] = *(const s8v*)&ah[kc][SW32(wm + mf * 16 + rl, kk)];
        #pragma unroll
        for (int mf = 0; mf < 4; ++mf)
            #pragma unroll
            for (int nf = 0; nf < 4; ++nf)
                acc[mf][nf] = __builtin_amdgcn_mfma_f32_16x16x32_bf16(Ah[mf], Bh[nf], acc[mf][nf], 0, 0, 0);
    }

    #pragma unroll
    for (int mf = 0; mf < 4; ++mf) {
        int rr = rb * 128 + wm + mf * 16 + kq * 4;
        #pragma unroll
        for (int nf = 0; nf < 4; ++nf) {
            int c = sb * 128 + wn + nf * 16 + rl;
            #pragma unroll
            for (int r = 0; r < 4; ++r)
                __builtin_nontemporal_store(acc[mf][nf][r], &y[(size_t)(rr + r) * S_LEN + c]);
        }
    }
}

extern "C" void kernel_launch(void* const* d_in, const int* in_sizes, int n_in,
                              void* d_out, int out_size, void* d_ws, size_t ws_size,
                              hipStream_t stream) {
    const float* x      = (const float*)d_in[0];
    const float* w_real = (const float*)d_in[1];
    const float* w_imag = (const float*)d_in[2];
    float* y = (float*)d_out;

    const size_t TBL = (size_t)S_LEN * 128;       // 1M elems
    char* w0 = (char*)d_ws;
    short* T1fH    = (short*)w0;                  // 2MB each half (K3 B fragment image)
    short* T1fL    = T1fH + TBL;
    _Float16* Bimg = (_Float16*)(T1fL + TBL);     // 2MB (K1 B LDS image)
    float* Xt      = (float*)(Bimg + TBL);        // 2MB: [64 m][4096 row][re,im]
    float* tab     = Xt + (size_t)64 * 4096 * 2;  // 32KB
    float* P       = tab + S_LEN;                 // 16MB (8 slices)
    // After ksum_t, P is dead: wT (8MB) + C2 (4MB) overlap it.
    float* wTr     = P;                           // 4MB: [4 h][64 m][4096 io]
    float* wTi     = wTr + (size_t)4 * 64 * 4096;
    short* C2h     = (short*)(wTi + (size_t)4 * 64 * 4096);
    short* C2l     = C2h + TBL;
    const size_t TOTAL = (size_t)((char*)(P + 8 * (size_t)4096 * 128) - w0);  // ~24MB
    if (ws_size < TOTAL) {
        fprintf(stderr, "kernel_launch: ws too small (%zu < %zu bytes)\n", ws_size, TOTAL);
        return;
    }

    gen_master<<<S_LEN / 256, 256, 0, stream>>>(tab);
    gen_tables<<<(S_LEN * 128) / 256, 256, 0, stream>>>(tab, T1fH, T1fL, Bimg);
    dft_fwd_mfma<<<dim3(64, 8), 512, 0, stream>>>(x, Bimg, P);
    ksum_t<<<128, 256, 0, stream>>>(P, Xt);                       // P -> Xt (P now dead)
    wtrans<<<dim3(64, 8), 256, 0, stream>>>(w_real, w_imag, wTr, wTi);  // into P region
    mode_contract<<<dim3(NM, 4), 256, 0, stream>>>(Xt, wTr, wTi, C2h, C2l);
    idft_mfma<<<dim3(64, 32), 256, 0, stream>>>(C2h, C2l, T1fH, T1fL, y);
}

// Round 26
// 107.107 us; speedup vs baseline: 1.0976x; 1.0276x over previous
//
#include <hip/hip_runtime.h>
#include <cstdio>

// B=32, Cin=128, S=8192, H=4, Hc=32, M=64, Cout=128
#define S_LEN 8192
#define NM 64

typedef short s8v __attribute__((ext_vector_type(8)));   // 8 bf16
typedef float f4  __attribute__((ext_vector_type(4)));
typedef _Float16 h8 __attribute__((ext_vector_type(8))); // 8 fp16

static __device__ inline unsigned short f2bf(float f) {  // RNE fp32->bf16
    unsigned int u = __builtin_bit_cast(unsigned int, f);
    u = (u + 0x7FFFu + ((u >> 16) & 1u)) >> 16;
    return (unsigned short)u;
}

// C2-image swizzle: [128 r][32 k] tile, XOR k-bits 3..4 with (r>>1)&3
#define SW32(r, k) (((r) * 32) + ((k) ^ ((((r) >> 1) & 3) << 3)))

static __device__ __forceinline__ void glds16(const void* g, void* l) {
    __builtin_amdgcn_global_load_lds(
        (const __attribute__((address_space(1))) unsigned int*)g,
        (__attribute__((address_space(3))) unsigned int*)l, 16, 0, 0);
}

// ---------------- master trig table: tab[p] = cos(2*pi*p/8192) ----------------
__global__ __launch_bounds__(256) void gen_master(float* __restrict__ tab) {
    int p = blockIdx.x * 256 + threadIdx.x;
    tab[p] = cosf((float)p * (6.28318530717958647692f / (float)S_LEN));
}

// ---------------- fused table gen: T1frag hi (K3 B, fragment order) + Bimg (K1 B) ----------
__global__ __launch_bounds__(256) void gen_tables(const float* __restrict__ tab,
                                                  short* __restrict__ T1fH,
                                                  _Float16* __restrict__ Bimg) {
    int tid = blockIdx.x * 256 + threadIdx.x;     // 1M
    {   // T1frag element (bf16 hi only)
        int tile = tid >> 12;
        int sb = tile >> 2, kc = tile & 3;
        int uw = tid & 4095;
        int c = uw >> 5, rest = uw & 31;
        int k = kc * 32 + rest;
        int s = sb * 128 + c;
        int m = k >> 1;
        int p = (m * s + ((k & 1) << 11)) & (S_LEN - 1);
        T1fH[tid] = (short)f2bf(tab[p]);
    }
    {   // Bimg element
        int tk = tid >> 13;
        int us = tid & 8191;
        int c = us >> 6;
        int wl = us & 63;
        int slot = wl >> 3, e = wl & 7;
        int k = ((slot ^ (c & 7)) << 3) | e;      // invert swizzle
        int kg = tk * 64 + k;
        int m = c >> 1;
        int p = (m * kg + ((c & 1) << 11)) & (S_LEN - 1);
        Bimg[tid] = (_Float16)tab[p];
    }
}

// ---------------- K1: P[ks] = x * B1 ; BM=64 BN=128 BK=64; A SINGLE fp16 (R24) ----------------
__global__ __launch_bounds__(512, 4) void dft_fwd_mfma(const float* __restrict__ x,
        const _Float16* __restrict__ Bimg, float* __restrict__ P) {
    __shared__ _Float16 ab[2][4096];                  // A fp16 [64r][64k], 8KB/buf
    __shared__ _Float16 bb[2][8192];                  // B [128c][64k], 16KB/buf
    const int t = threadIdx.x;
    const int lane = t & 63, w = t >> 6;
    const int rl = lane & 15, kq = lane >> 4;
    const int wr = w >> 2, wc = w & 3;
    const int row0 = blockIdx.x * 64;
    const int ks = blockIdx.y;                        // 0..7
    const int rA = t >> 3, sA = t & 7;
    const size_t xrow = (size_t)(row0 + rA) * S_LEN + (size_t)ks * 1024 + (size_t)sA * 8;
    const int usA = rA * 64 + ((sA ^ (rA & 7)) << 3);
    const size_t bby = (size_t)ks * 16 * 16384 + (size_t)t * 32;

    f4 acc[2][2];
    #pragma unroll
    for (int i = 0; i < 2; ++i)
        #pragma unroll
        for (int j = 0; j < 2; ++j) acc[i][j] = (f4){0.f, 0.f, 0.f, 0.f};

    f4 aP[3][2];
    h8 bP[2][2];

    #define LA_(SC, A0, A1) { A0 = *(const f4*)&x[xrow + (size_t)(SC) * 64];       \
                              A1 = *(const f4*)&x[xrow + (size_t)(SC) * 64 + 4]; }
    #define LB_(SC, B0, B1) { const char* g = (const char*)Bimg + bby +            \
                                  (size_t)(SC) * 16384;                            \
                              B0 = *(const h8*)g; B1 = *(const h8*)(g + 16); }
    #define CV_(A0, A1, NXT) { h8 hv;                                              \
        _Pragma("unroll")                                                          \
        for (int e = 0; e < 4; ++e) hv[e] = (_Float16)A0[e];                       \
        _Pragma("unroll")                                                          \
        for (int e = 0; e < 4; ++e) hv[4 + e] = (_Float16)A1[e];                   \
        *(h8*)&ab[NXT][usA] = hv; }
    #define WB_(B0, B1, NXT) { *(h8*)&bb[NXT][t * 16] = B0;                        \
                               *(h8*)&bb[NXT][t * 16 + 8] = B1; }
    #define MM_(CUR) { _Pragma("unroll")                                           \
        for (int ksl = 0; ksl < 2; ++ksl) {                                        \
            const int sb_ = ksl * 4 + kq;                                          \
            h8 Av0, Av1, Bv0, Bv1;                                                 \
            { int r = wr * 32 + rl;      int u = r * 64 + ((sb_ ^ (r & 7)) << 3);  \
              Av0 = *(const h8*)&ab[CUR][u]; }                                     \
            { int r = wr * 32 + 16 + rl; int u = r * 64 + ((sb_ ^ (r & 7)) << 3);  \
              Av1 = *(const h8*)&ab[CUR][u]; }                                     \
            { int c = wc * 32 + rl;      int u = c * 64 + ((sb_ ^ (c & 7)) << 3);  \
              Bv0 = *(const h8*)&bb[CUR][u]; }                                     \
            { int c = wc * 32 + 16 + rl; int u = c * 64 + ((sb_ ^ (c & 7)) << 3);  \
              Bv1 = *(const h8*)&bb[CUR][u]; }                                     \
            acc[0][0] = __builtin_amdgcn_mfma_f32_16x16x32_f16(Av0, Bv0, acc[0][0], 0, 0, 0); \
            acc[0][1] = __builtin_amdgcn_mfma_f32_16x16x32_f16(Av0, Bv1, acc[0][1], 0, 0, 0); \
            acc[1][0] = __builtin_amdgcn_mfma_f32_16x16x32_f16(Av1, Bv0, acc[1][0], 0, 0, 0); \
            acc[1][1] = __builtin_amdgcn_mfma_f32_16x16x32_f16(Av1, Bv1, acc[1][1], 0, 0, 0); \
        } }
    #define BAR_ __builtin_amdgcn_sched_barrier(0);                                \
        asm volatile("s_waitcnt lgkmcnt(0)" ::: "memory");                         \
        __builtin_amdgcn_sched_barrier(0);                                         \
        __builtin_amdgcn_s_barrier();                                              \
        __builtin_amdgcn_sched_barrier(0);

    {
        f4 t0a, t0b; h8 tb0a, tb0b;
        LA_(0, t0a, t0b) LB_(0, tb0a, tb0b)
        LA_(1, aP[1][0], aP[1][1]) LA_(2, aP[2][0], aP[2][1])
        LB_(1, bP[1][0], bP[1][1])
        __builtin_amdgcn_sched_barrier(0);
        CV_(t0a, t0b, 0) WB_(tb0a, tb0b, 0)
        BAR_
    }
    #pragma unroll
    for (int s = 0; s < 16; ++s) {
        if (s + 3 <= 15) LA_(s + 3, aP[(s + 3) % 3][0], aP[(s + 3) % 3][1])
        if (s + 2 <= 15) LB_(s + 2, bP[(s + 2) & 1][0], bP[(s + 2) & 1][1])
        __builtin_amdgcn_sched_barrier(0);
        if (s + 1 <= 15) { CV_(aP[(s + 1) % 3][0], aP[(s + 1) % 3][1], (s + 1) & 1)
                           WB_(bP[(s + 1) & 1][0], bP[(s + 1) & 1][1], (s + 1) & 1) }
        MM_(s & 1)
        if (s < 15) { BAR_ }
    }

    float* Pks = P + (size_t)ks * 524288;
    #pragma unroll
    for (int mf = 0; mf < 2; ++mf)
        #pragma unroll
        for (int nf = 0; nf < 2; ++nf)
            #pragma unroll
            for (int r = 0; r < 4; ++r)
                Pks[(size_t)(row0 + wr * 32 + mf * 16 + kq * 4 + r) * 128
                    + wc * 32 + nf * 16 + rl] = acc[mf][nf][r];
}

// ---------------- ksum_t: Xt[m][row][re,im] = sum_ks P[ks][row][2m|2m+1] (LDS transpose) ----
__global__ __launch_bounds__(256) void ksum_t(const float* __restrict__ P,
                                              float* __restrict__ Xt) {
    __shared__ float xt[32][130];                 // +2 pad
    const int row0 = blockIdx.x * 32;
    const int t = threadIdx.x;
    #pragma unroll
    for (int it = 0; it < 16; ++it) {
        int li = t + it * 256;                    // 0..4095 = 32 rows x 128 cols
        int r = li >> 7, c = li & 127;
        float s = 0.f;
        #pragma unroll
        for (int ks = 0; ks < 8; ++ks)
            s += P[(size_t)ks * 524288 + (size_t)(row0 + r) * 128 + c];
        xt[r][c] = s;
    }
    __syncthreads();
    const int m = t >> 2, q = t & 3;              // m 0..63, row-quad q
    #pragma unroll
    for (int j = 0; j < 8; ++j) {
        int r = q * 8 + j;
        float2 v = make_float2(xt[r][2 * m], xt[r][2 * m + 1]);
        *(float2*)&Xt[((size_t)m * 4096 + row0 + r) * 2] = v;
    }
}

// ---------------- wtrans: wT[h][m][io] = w[h][i][o][m] (LDS 64x64 tile transpose) ----------
__global__ __launch_bounds__(256) void wtrans(const float* __restrict__ w_real,
                                              const float* __restrict__ w_imag,
                                              float* __restrict__ wTr,
                                              float* __restrict__ wTi) {
    __shared__ float tile[64][65];
    const int io0 = blockIdx.x * 64;              // 0..4032
    const int h = blockIdx.y >> 1;
    const float* src = (blockIdx.y & 1) ? w_imag : w_real;
    float* dst = (blockIdx.y & 1) ? wTi : wTr;
    const int t = threadIdx.x;
    #pragma unroll
    for (int it = 0; it < 16; ++it) {
        int li = t + it * 256;                    // 0..4095
        int r = li >> 6, c = li & 63;             // r: io offset, c: m
        tile[r][c] = src[((size_t)h * 4096 + io0 + r) * 64 + c];
    }
    __syncthreads();
    #pragma unroll
    for (int it = 0; it < 16; ++it) {
        int li = t + it * 256;
        int mr = li >> 6, ioc = li & 63;
        dst[((size_t)h * 64 + mr) * 4096 + io0 + ioc] = tile[ioc][mr];
    }
}

// ---------------- K2: mode contraction (coalesced) -> C2 image (bf16 hi only) --------------
__global__ __launch_bounds__(256) void mode_contract(const float* __restrict__ Xt,
        const float* __restrict__ wTr, const float* __restrict__ wTi,
        short* __restrict__ C2h) {
    __shared__ float xr[32][128], xi[32][128];
    __shared__ float wr[128][32], wi[128][32];
    const int m = blockIdx.x, h = blockIdx.y, t = threadIdx.x;
    #pragma unroll
    for (int it = 0; it < 16; ++it) {
        int li = t + it * 256;                    // 0..4095
        const float2 v = *(const float2*)&Xt[((size_t)m * 4096 + li) * 2];
        xr[li >> 7][li & 127] = v.x;
        xi[li >> 7][li & 127] = v.y;
        const size_t woff = (size_t)(h * 64 + m) * 4096 + li;   // li = i2*32+o
        wr[li >> 5][li & 31] = wTr[woff];
        wi[li >> 5][li & 31] = wTi[woff];
    }
    __syncthreads();
    const int o = t & 31;
    const int b0 = (t >> 5) * 4;
    float re[4] = {0.f, 0.f, 0.f, 0.f}, im[4] = {0.f, 0.f, 0.f, 0.f};
    for (int i = 0; i < 128; ++i) {
        float wrv = wr[i][o], wiv = wi[i][o];
        #pragma unroll
        for (int j = 0; j < 4; ++j) {
            float a = xr[b0 + j][i], c = xi[b0 + j][i];
            re[j] += a * wrv - c * wiv;
            im[j] += a * wiv + c * wrv;
        }
    }
    const float alpha = (m == 0) ? (1.0f / (float)S_LEN) : (2.0f / (float)S_LEN);
    const int kc = m >> 4;
    const int lk = (2 * m) & 31;
    #pragma unroll
    for (int j = 0; j < 4; ++j) {
        int row = (b0 + j) * 128 + h * 32 + o;
        float vr = alpha * re[j], vi = alpha * im[j];
        int rb = row >> 7, lr_ = row & 127;
        size_t ui = ((size_t)(rb * 4 + kc) * 4096 + SW32(lr_, lk)) >> 1;   // uint index
        ((unsigned int*)C2h)[ui] = ((unsigned int)f2bf(vi) << 16) | f2bf(vr);
    }
}

// ---------------- K3: y = C2[4096][128] * Basis[128][8192]; SINGLE bf16 (R25) ----------
__global__ __launch_bounds__(256, 4) void idft_mfma(const short* __restrict__ C2h,
        const short* __restrict__ T1fH, float* __restrict__ y) {
    __shared__ short ah[4][4096];                 // 4 kc tiles x 8KB = 32KB
    const int t = threadIdx.x;
    const int lane = t & 63, w = t >> 6;
    const int rl = lane & 15, kq = lane >> 4;
    const int wm = (w >> 1) * 64, wn = (w & 1) * 64;
    const int sb = blockIdx.x, rb = blockIdx.y;

    #pragma unroll
    for (int kc = 0; kc < 4; ++kc) {
        const size_t ta = (size_t)(rb * 4 + kc) * 8192;
        const int wo = w * 2048 + lane * 16;
        glds16((const char*)C2h + ta + wo,        (char*)&ah[kc][0] + w * 2048);
        glds16((const char*)C2h + ta + wo + 1024, (char*)&ah[kc][0] + w * 2048 + 1024);
    }
    __syncthreads();   // the ONLY barrier

    f4 acc[4][4];
    #pragma unroll
    for (int i = 0; i < 4; ++i)
        #pragma unroll
        for (int j = 0; j < 4; ++j) acc[i][j] = (f4){0.f, 0.f, 0.f, 0.f};

    #pragma unroll
    for (int kc = 0; kc < 4; ++kc) {
        s8v Bh[4];
        const size_t tb = (size_t)(sb * 4 + kc) * 8192 + (size_t)rl * 64 + (size_t)kq * 16;
        #pragma unroll
        for (int nf = 0; nf < 4; ++nf)
            Bh[nf] = *(const s8v*)((const char*)T1fH + tb + (size_t)(wn + nf * 16) * 64);
        const int kk = kq * 8;
        s8v Ah[4];
        #pragma unroll
        for (int mf = 0; mf < 4; ++mf)
            Ah[mf] = *(const s8v*)&ah[kc][SW32(wm + mf * 16 + rl, kk)];
        #pragma unroll
        for (int mf = 0; mf < 4; ++mf)
            #pragma unroll
            for (int nf = 0; nf < 4; ++nf)
                acc[mf][nf] = __builtin_amdgcn_mfma_f32_16x16x32_bf16(Ah[mf], Bh[nf], acc[mf][nf], 0, 0, 0);
    }

    #pragma unroll
    for (int mf = 0; mf < 4; ++mf) {
        int rr = rb * 128 + wm + mf * 16 + kq * 4;
        #pragma unroll
        for (int nf = 0; nf < 4; ++nf) {
            int c = sb * 128 + wn + nf * 16 + rl;
            #pragma unroll
            for (int r = 0; r < 4; ++r)
                __builtin_nontemporal_store(acc[mf][nf][r], &y[(size_t)(rr + r) * S_LEN + c]);
        }
    }
}

extern "C" void kernel_launch(void* const* d_in, const int* in_sizes, int n_in,
                              void* d_out, int out_size, void* d_ws, size_t ws_size,
                              hipStream_t stream) {
    const float* x      = (const float*)d_in[0];
    const float* w_real = (const float*)d_in[1];
    const float* w_imag = (const float*)d_in[2];
    float* y = (float*)d_out;

    const size_t TBL = (size_t)S_LEN * 128;       // 1M elems
    char* w0 = (char*)d_ws;
    short* T1fH    = (short*)w0;                  // 2MB (K3 B fragment image, bf16 hi)
    _Float16* Bimg = (_Float16*)(T1fH + TBL);     // 2MB (K1 B LDS image)
    float* Xt      = (float*)(Bimg + TBL);        // 2MB: [64 m][4096 row][re,im]
    float* tab     = Xt + (size_t)64 * 4096 * 2;  // 32KB
    float* P       = tab + S_LEN;                 // 16MB (8 slices)
    // After ksum_t, P is dead: wT (8MB) + C2 (2MB) overlap it.
    float* wTr     = P;                           // 4MB: [4 h][64 m][4096 io]
    float* wTi     = wTr + (size_t)4 * 64 * 4096;
    short* C2h     = (short*)(wTi + (size_t)4 * 64 * 4096);
    const size_t TOTAL = (size_t)((char*)(P + 8 * (size_t)4096 * 128) - w0);  // ~22MB
    if (ws_size < TOTAL) {
        fprintf(stderr, "kernel_launch: ws too small (%zu < %zu bytes)\n", ws_size, TOTAL);
        return;
    }

    gen_master<<<S_LEN / 256, 256, 0, stream>>>(tab);
    gen_tables<<<(S_LEN * 128) / 256, 256, 0, stream>>>(tab, T1fH, Bimg);
    dft_fwd_mfma<<<dim3(64, 8), 512, 0, stream>>>(x, Bimg, P);
    ksum_t<<<128, 256, 0, stream>>>(P, Xt);                       // P -> Xt (P now dead)
    wtrans<<<dim3(64, 8), 256, 0, stream>>>(w_real, w_imag, wTr, wTi);  // into P region
    mode_contract<<<dim3(NM, 4), 256, 0, stream>>>(Xt, wTr, wTi, C2h);
    idft_mfma<<<dim3(64, 32), 256, 0, stream>>>(C2h, T1fH, y);
}

// Round 28
// 105.113 us; speedup vs baseline: 1.1184x; 1.0190x over previous
//
#include <hip/hip_runtime.h>
#include <cstdio>

// B=32, Cin=128, S=8192, H=4, Hc=32, M=64, Cout=128
#define S_LEN 8192
#define NM 64

typedef short s8v __attribute__((ext_vector_type(8)));   // 8 bf16
typedef float f4  __attribute__((ext_vector_type(4)));
typedef _Float16 h8 __attribute__((ext_vector_type(8))); // 8 fp16

static __device__ inline unsigned short f2bf(float f) {  // RNE fp32->bf16
    unsigned int u = __builtin_bit_cast(unsigned int, f);
    u = (u + 0x7FFFu + ((u >> 16) & 1u)) >> 16;
    return (unsigned short)u;
}
static __device__ inline float bf2f(unsigned short h) {
    unsigned int u = ((unsigned int)h) << 16;
    return __builtin_bit_cast(float, u);
}

// C2-image swizzle: [128 r][32 k] tile, XOR k-bits 3..4 with (r>>1)&3
#define SW32(r, k) (((r) * 32) + ((k) ^ ((((r) >> 1) & 3) << 3)))

static __device__ __forceinline__ void glds16(const void* g, void* l) {
    __builtin_amdgcn_global_load_lds(
        (const __attribute__((address_space(1))) unsigned int*)g,
        (__attribute__((address_space(3))) unsigned int*)l, 16, 0, 0);
}

// ---------------- master trig table: tab[p] = cos(2*pi*p/8192) ----------------
__global__ __launch_bounds__(256) void gen_master(float* __restrict__ tab) {
    int p = blockIdx.x * 256 + threadIdx.x;
    tab[p] = cosf((float)p * (6.28318530717958647692f / (float)S_LEN));
}

// ---------------- fused table gen: T1frag hi (K3 B, fragment order) + Bimg (K1 B) ----------
__global__ __launch_bounds__(256) void gen_tables(const float* __restrict__ tab,
                                                  short* __restrict__ T1fH,
                                                  _Float16* __restrict__ Bimg) {
    int tid = blockIdx.x * 256 + threadIdx.x;     // 1M
    {   // T1frag element (bf16 hi only)
        int tile = tid >> 12;
        int sb = tile >> 2, kc = tile & 3;
        int uw = tid & 4095;
        int c = uw >> 5, rest = uw & 31;
        int k = kc * 32 + rest;
        int s = sb * 128 + c;
        int m = k >> 1;
        int p = (m * s + ((k & 1) << 11)) & (S_LEN - 1);
        T1fH[tid] = (short)f2bf(tab[p]);
    }
    {   // Bimg element
        int tk = tid >> 13;
        int us = tid & 8191;
        int c = us >> 6;
        int wl = us & 63;
        int slot = wl >> 3, e = wl & 7;
        int k = ((slot ^ (c & 7)) << 3) | e;      // invert swizzle
        int kg = tk * 64 + k;
        int m = c >> 1;
        int p = (m * kg + ((c & 1) << 11)) & (S_LEN - 1);
        Bimg[tid] = (_Float16)tab[p];
    }
}

// ---------------- K1: P[ks] = x * B1 ; BM=64 BN=128 BK=64; A SINGLE fp16; P bf16 ------------
__global__ __launch_bounds__(512, 4) void dft_fwd_mfma(const float* __restrict__ x,
        const _Float16* __restrict__ Bimg, short* __restrict__ P) {
    __shared__ _Float16 ab[2][4096];                  // A fp16 [64r][64k], 8KB/buf
    __shared__ _Float16 bb[2][8192];                  // B [128c][64k], 16KB/buf
    const int t = threadIdx.x;
    const int lane = t & 63, w = t >> 6;
    const int rl = lane & 15, kq = lane >> 4;
    const int wr = w >> 2, wc = w & 3;
    const int row0 = blockIdx.x * 64;
    const int ks = blockIdx.y;                        // 0..7
    const int rA = t >> 3, sA = t & 7;
    const size_t xrow = (size_t)(row0 + rA) * S_LEN + (size_t)ks * 1024 + (size_t)sA * 8;
    const int usA = rA * 64 + ((sA ^ (rA & 7)) << 3);
    const size_t bby = (size_t)ks * 16 * 16384 + (size_t)t * 32;

    f4 acc[2][2];
    #pragma unroll
    for (int i = 0; i < 2; ++i)
        #pragma unroll
        for (int j = 0; j < 2; ++j) acc[i][j] = (f4){0.f, 0.f, 0.f, 0.f};

    f4 aP[3][2];
    h8 bP[2][2];

    #define LA_(SC, A0, A1) { A0 = *(const f4*)&x[xrow + (size_t)(SC) * 64];       \
                              A1 = *(const f4*)&x[xrow + (size_t)(SC) * 64 + 4]; }
    #define LB_(SC, B0, B1) { const char* g = (const char*)Bimg + bby +            \
                                  (size_t)(SC) * 16384;                            \
                              B0 = *(const h8*)g; B1 = *(const h8*)(g + 16); }
    #define CV_(A0, A1, NXT) { h8 hv;                                              \
        _Pragma("unroll")                                                          \
        for (int e = 0; e < 4; ++e) hv[e] = (_Float16)A0[e];                       \
        _Pragma("unroll")                                                          \
        for (int e = 0; e < 4; ++e) hv[4 + e] = (_Float16)A1[e];                   \
        *(h8*)&ab[NXT][usA] = hv; }
    #define WB_(B0, B1, NXT) { *(h8*)&bb[NXT][t * 16] = B0;                        \
                               *(h8*)&bb[NXT][t * 16 + 8] = B1; }
    #define MM_(CUR) { _Pragma("unroll")                                           \
        for (int ksl = 0; ksl < 2; ++ksl) {                                        \
            const int sb_ = ksl * 4 + kq;                                          \
            h8 Av0, Av1, Bv0, Bv1;                                                 \
            { int r = wr * 32 + rl;      int u = r * 64 + ((sb_ ^ (r & 7)) << 3);  \
              Av0 = *(const h8*)&ab[CUR][u]; }                                     \
            { int r = wr * 32 + 16 + rl; int u = r * 64 + ((sb_ ^ (r & 7)) << 3);  \
              Av1 = *(const h8*)&ab[CUR][u]; }                                     \
            { int c = wc * 32 + rl;      int u = c * 64 + ((sb_ ^ (c & 7)) << 3);  \
              Bv0 = *(const h8*)&bb[CUR][u]; }                                     \
            { int c = wc * 32 + 16 + rl; int u = c * 64 + ((sb_ ^ (c & 7)) << 3);  \
              Bv1 = *(const h8*)&bb[CUR][u]; }                                     \
            acc[0][0] = __builtin_amdgcn_mfma_f32_16x16x32_f16(Av0, Bv0, acc[0][0], 0, 0, 0); \
            acc[0][1] = __builtin_amdgcn_mfma_f32_16x16x32_f16(Av0, Bv1, acc[0][1], 0, 0, 0); \
            acc[1][0] = __builtin_amdgcn_mfma_f32_16x16x32_f16(Av1, Bv0, acc[1][0], 0, 0, 0); \
            acc[1][1] = __builtin_amdgcn_mfma_f32_16x16x32_f16(Av1, Bv1, acc[1][1], 0, 0, 0); \
        } }
    #define BAR_ __builtin_amdgcn_sched_barrier(0);                                \
        asm volatile("s_waitcnt lgkmcnt(0)" ::: "memory");                         \
        __builtin_amdgcn_sched_barrier(0);                                         \
        __builtin_amdgcn_s_barrier();                                              \
        __builtin_amdgcn_sched_barrier(0);

    {
        f4 t0a, t0b; h8 tb0a, tb0b;
        LA_(0, t0a, t0b) LB_(0, tb0a, tb0b)
        LA_(1, aP[1][0], aP[1][1]) LA_(2, aP[2][0], aP[2][1])
        LB_(1, bP[1][0], bP[1][1])
        __builtin_amdgcn_sched_barrier(0);
        CV_(t0a, t0b, 0) WB_(tb0a, tb0b, 0)
        BAR_
    }
    #pragma unroll
    for (int s = 0; s < 16; ++s) {
        if (s + 3 <= 15) LA_(s + 3, aP[(s + 3) % 3][0], aP[(s + 3) % 3][1])
        if (s + 2 <= 15) LB_(s + 2, bP[(s + 2) & 1][0], bP[(s + 2) & 1][1])
        __builtin_amdgcn_sched_barrier(0);
        if (s + 1 <= 15) { CV_(aP[(s + 1) % 3][0], aP[(s + 1) % 3][1], (s + 1) & 1)
                           WB_(bP[(s + 1) & 1][0], bP[(s + 1) & 1][1], (s + 1) & 1) }
        MM_(s & 1)
        if (s < 15) { BAR_ }
    }

    // epilogue: bf16 partials. SLICE STRIDE = 524288 ELEMENTS (4096x128) — R27 bug was 262144.
    short* Pks = P + (size_t)ks * 524288;
    #pragma unroll
    for (int mf = 0; mf < 2; ++mf)
        #pragma unroll
        for (int nf = 0; nf < 2; ++nf)
            #pragma unroll
            for (int r = 0; r < 4; ++r)
                Pks[(size_t)(row0 + wr * 32 + mf * 16 + kq * 4 + r) * 128
                    + wc * 32 + nf * 16 + rl] = (short)f2bf(acc[mf][nf][r]);
}

// ---------------- ksum_t: Xt[m][row][re,im] = sum_ks bf16-P (uint-pair loads) ----------------
__global__ __launch_bounds__(256) void ksum_t(const short* __restrict__ P,
                                              float* __restrict__ Xt) {
    __shared__ float xt[32][130];                 // +2 pad
    const int row0 = blockIdx.x * 32;
    const int t = threadIdx.x;
    #pragma unroll
    for (int it = 0; it < 8; ++it) {
        int li = t + it * 256;                    // 0..2047 = 32 rows x 64 col-pairs
        int r = li >> 6, c2 = li & 63;
        float s0 = 0.f, s1 = 0.f;
        #pragma unroll
        for (int ks = 0; ks < 8; ++ks) {
            unsigned int v = *(const unsigned int*)
                (P + (size_t)ks * 524288 + (size_t)(row0 + r) * 128 + c2 * 2);
            s0 += bf2f((unsigned short)(v & 0xFFFFu));
            s1 += bf2f((unsigned short)(v >> 16));
        }
        xt[r][2 * c2]     = s0;
        xt[r][2 * c2 + 1] = s1;
    }
    __syncthreads();
    const int m = t >> 2, q = t & 3;              // m 0..63, row-quad q
    #pragma unroll
    for (int j = 0; j < 8; ++j) {
        int r = q * 8 + j;
        float2 v = make_float2(xt[r][2 * m], xt[r][2 * m + 1]);
        *(float2*)&Xt[((size_t)m * 4096 + row0 + r) * 2] = v;
    }
}

// ---------------- wtrans: wT[h][m][io] = w[h][i][o][m] (LDS 64x64 tile transpose) ----------
__global__ __launch_bounds__(256) void wtrans(const float* __restrict__ w_real,
                                              const float* __restrict__ w_imag,
                                              float* __restrict__ wTr,
                                              float* __restrict__ wTi) {
    __shared__ float tile[64][65];
    const int io0 = blockIdx.x * 64;              // 0..4032
    const int h = blockIdx.y >> 1;
    const float* src = (blockIdx.y & 1) ? w_imag : w_real;
    float* dst = (blockIdx.y & 1) ? wTi : wTr;
    const int t = threadIdx.x;
    #pragma unroll
    for (int it = 0; it < 16; ++it) {
        int li = t + it * 256;                    // 0..4095
        int r = li >> 6, c = li & 63;             // r: io offset, c: m
        tile[r][c] = src[((size_t)h * 4096 + io0 + r) * 64 + c];
    }
    __syncthreads();
    #pragma unroll
    for (int it = 0; it < 16; ++it) {
        int li = t + it * 256;
        int mr = li >> 6, ioc = li & 63;
        dst[((size_t)h * 64 + mr) * 4096 + io0 + ioc] = tile[ioc][mr];
    }
}

// ---------------- K2: mode contraction (coalesced) -> C2 image (bf16 hi only) --------------
__global__ __launch_bounds__(256) void mode_contract(const float* __restrict__ Xt,
        const float* __restrict__ wTr, const float* __restrict__ wTi,
        short* __restrict__ C2h) {
    __shared__ float xr[32][128], xi[32][128];
    __shared__ float wr[128][32], wi[128][32];
    const int m = blockIdx.x, h = blockIdx.y, t = threadIdx.x;
    #pragma unroll
    for (int it = 0; it < 16; ++it) {
        int li = t + it * 256;                    // 0..4095
        const float2 v = *(const float2*)&Xt[((size_t)m * 4096 + li) * 2];
        xr[li >> 7][li & 127] = v.x;
        xi[li >> 7][li & 127] = v.y;
        const size_t woff = (size_t)(h * 64 + m) * 4096 + li;   // li = i2*32+o
        wr[li >> 5][li & 31] = wTr[woff];
        wi[li >> 5][li & 31] = wTi[woff];
    }
    __syncthreads();
    const int o = t & 31;
    const int b0 = (t >> 5) * 4;
    float re[4] = {0.f, 0.f, 0.f, 0.f}, im[4] = {0.f, 0.f, 0.f, 0.f};
    for (int i = 0; i < 128; ++i) {
        float wrv = wr[i][o], wiv = wi[i][o];
        #pragma unroll
        for (int j = 0; j < 4; ++j) {
            float a = xr[b0 + j][i], c = xi[b0 + j][i];
            re[j] += a * wrv - c * wiv;
            im[j] += a * wiv + c * wrv;
        }
    }
    const float alpha = (m == 0) ? (1.0f / (float)S_LEN) : (2.0f / (float)S_LEN);
    const int kc = m >> 4;
    const int lk = (2 * m) & 31;
    #pragma unroll
    for (int j = 0; j < 4; ++j) {
        int row = (b0 + j) * 128 + h * 32 + o;
        float vr = alpha * re[j], vi = alpha * im[j];
        int rb = row >> 7, lr_ = row & 127;
        size_t ui = ((size_t)(rb * 4 + kc) * 4096 + SW32(lr_, lk)) >> 1;   // uint index
        ((unsigned int*)C2h)[ui] = ((unsigned int)f2bf(vi) << 16) | f2bf(vr);
    }
}

// ---------------- K3: y = C2[4096][128] * Basis[128][8192]; SINGLE bf16 (R25) ----------
__global__ __launch_bounds__(256, 4) void idft_mfma(const short* __restrict__ C2h,
        const short* __restrict__ T1fH, float* __restrict__ y) {
    __shared__ short ah[4][4096];                 // 4 kc tiles x 8KB = 32KB
    const int t = threadIdx.x;
    const int lane = t & 63, w = t >> 6;
    const int rl = lane & 15, kq = lane >> 4;
    const int wm = (w >> 1) * 64, wn = (w & 1) * 64;
    const int sb = blockIdx.x, rb = blockIdx.y;

    #pragma unroll
    for (int kc = 0; kc < 4; ++kc) {
        const size_t ta = (size_t)(rb * 4 + kc) * 8192;
        const int wo = w * 2048 + lane * 16;
        glds16((const char*)C2h + ta + wo,        (char*)&ah[kc][0] + w * 2048);
        glds16((const char*)C2h + ta + wo + 1024, (char*)&ah[kc][0] + w * 2048 + 1024);
    }
    __syncthreads();   // the ONLY barrier

    f4 acc[4][4];
    #pragma unroll
    for (int i = 0; i < 4; ++i)
        #pragma unroll
        for (int j = 0; j < 4; ++j) acc[i][j] = (f4){0.f, 0.f, 0.f, 0.f};

    #pragma unroll
    for (int kc = 0; kc < 4; ++kc) {
        s8v Bh[4];
        const size_t tb = (size_t)(sb * 4 + kc) * 8192 + (size_t)rl * 64 + (size_t)kq * 16;
        #pragma unroll
        for (int nf = 0; nf < 4; ++nf)
            Bh[nf] = *(const s8v*)((const char*)T1fH + tb + (size_t)(wn + nf * 16) * 64);
        const int kk = kq * 8;
        s8v Ah[4];
        #pragma unroll
        for (int mf = 0; mf < 4; ++mf)
            Ah[mf] = *(const s8v*)&ah[kc][SW32(wm + mf * 16 + rl, kk)];
        #pragma unroll
        for (int mf = 0; mf < 4; ++mf)
            #pragma unroll
            for (int nf = 0; nf < 4; ++nf)
                acc[mf][nf] = __builtin_amdgcn_mfma_f32_16x16x32_bf16(Ah[mf], Bh[nf], acc[mf][nf], 0, 0, 0);
    }

    #pragma unroll
    for (int mf = 0; mf < 4; ++mf) {
        int rr = rb * 128 + wm + mf * 16 + kq * 4;
        #pragma unroll
        for (int nf = 0; nf < 4; ++nf) {
            int c = sb * 128 + wn + nf * 16 + rl;
            #pragma unroll
            for (int r = 0; r < 4; ++r)
                __builtin_nontemporal_store(acc[mf][nf][r], &y[(size_t)(rr + r) * S_LEN + c]);
        }
    }
}

extern "C" void kernel_launch(void* const* d_in, const int* in_sizes, int n_in,
                              void* d_out, int out_size, void* d_ws, size_t ws_size,
                              hipStream_t stream) {
    const float* x      = (const float*)d_in[0];
    const float* w_real = (const float*)d_in[1];
    const float* w_imag = (const float*)d_in[2];
    float* y = (float*)d_out;

    const size_t TBL = (size_t)S_LEN * 128;       // 1M elems
    char* w0 = (char*)d_ws;
    short* T1fH    = (short*)w0;                  // 2MB (K3 B fragment image, bf16 hi)
    _Float16* Bimg = (_Float16*)(T1fH + TBL);     // 2MB (K1 B LDS image)
    float* Xt      = (float*)(Bimg + TBL);        // 2MB: [64 m][4096 row][re,im]
    float* tab     = Xt + (size_t)64 * 4096 * 2;  // 32KB
    short* P       = (short*)(tab + S_LEN);       // 8MB (8 slices x 524288 bf16)
    // After ksum_t, P is dead: wT (8MB) overlaps it; C2 follows.
    float* wTr     = (float*)P;                   // 4MB: [4 h][64 m][4096 io]
    float* wTi     = wTr + (size_t)4 * 64 * 4096;
    short* C2h     = (short*)(wTi + (size_t)4 * 64 * 4096);   // 2MB
    const size_t TOTAL = (size_t)((char*)(C2h + TBL) - w0);   // ~16MB
    if (ws_size < TOTAL) {
        fprintf(stderr, "kernel_launch: ws too small (%zu < %zu bytes)\n", ws_size, TOTAL);
        return;
    }

    gen_master<<<S_LEN / 256, 256, 0, stream>>>(tab);
    gen_tables<<<(S_LEN * 128) / 256, 256, 0, stream>>>(tab, T1fH, Bimg);
    dft_fwd_mfma<<<dim3(64, 8), 512, 0, stream>>>(x, Bimg, P);
    ksum_t<<<128, 256, 0, stream>>>(P, Xt);                       // P -> Xt (P now dead)
    wtrans<<<dim3(64, 8), 256, 0, stream>>>(w_real, w_imag, wTr, wTi);  // into P region
    mode_contract<<<dim3(NM, 4), 256, 0, stream>>>(Xt, wTr, wTi, C2h);
    idft_mfma<<<dim3(64, 32), 256, 0, stream>>>(C2h, T1fH, y);
}